// Round 1
// baseline (165.313 us; speedup 1.0000x reference)
//
#include <hip/hip_runtime.h>
#include <hip/hip_fp16.h>

#define N_NODES 100000
#define CCH 64
#define E_EDGES 1600000
#define HH 8
#define ETHR 1024   // edge-kernel block size: 16 waves/block, 2 blocks/CU -> 100% occupancy

typedef float v4f __attribute__((ext_vector_type(4)));

// Split dense tables (total 2.0 MB, was 3.2 MB interleaved):
//   ps_t[n] : 8 B = p_src[4] fp16      (0.8 MB)
//   pd_t[n] : 8 B = p_dst[4] fp16      (0.8 MB)
//   q_t[n]  : 4 B = (q_src, q_dst) fp16 (0.4 MB)
// Rationale: 3.2 MB table vs 4 MiB per-XCD L2 + ~90 MB streaming pressure ->
// gather misses to HBM at line granularity. 2.0 MB (with a 0.4 MB ultra-hot
// q table) stays resident; streaming keeps nt evict-first hints.
union H4 { uint2 v;        __half h[4]; };
union H2 { unsigned int v; __half h[2]; };

__global__ __launch_bounds__(256) void node_pre(
    const float* __restrict__ x,
    const int* __restrict__ layer_idx_p,
    const float* __restrict__ psi_w,
    const float* __restrict__ psi_b,
    const float* __restrict__ delta_w,
    const float* __restrict__ u,
    uint2* __restrict__ ps_t,
    uint2* __restrict__ pd_t,
    unsigned int* __restrict__ q_t)
{
    __shared__ float4 s_w0[CCH];
    __shared__ float4 s_w1[CCH];
    __shared__ float  s_b0[CCH];
    __shared__ float  s_b1[CCH];

    int li = layer_idx_p[0];
    for (int i = threadIdx.x; i < 2 * CCH; i += blockDim.x) {
        float4 w = make_float4(psi_w[i * 4 + 0], psi_w[i * 4 + 1],
                               psi_w[i * 4 + 2], psi_w[i * 4 + 3]);
        float bb = psi_b[i] + delta_w[li * 2 * CCH + i] + u[li * 2 * CCH + i];
        if (i < CCH) { s_w0[i] = w; s_b0[i] = bb; }
        else         { s_w1[i - CCH] = w; s_b1[i - CCH] = bb; }
    }
    __syncthreads();

    int n = blockIdx.x * blockDim.x + threadIdx.x;
    if (n >= N_NODES) return;

    const float4* xr = (const float4*)(x + (size_t)n * CCH);
    float a0 = 0, a1 = 0, a2 = 0, a3 = 0, aq = 0;
    float c0 = 0, c1 = 0, c2 = 0, c3 = 0, cq = 0;
#pragma unroll
    for (int it = 0; it < CCH / 4; ++it) {
        float4 xv4 = xr[it];
        float xv[4] = { xv4.x, xv4.y, xv4.z, xv4.w };
#pragma unroll
        for (int j = 0; j < 4; ++j) {
            int c = it * 4 + j;
            float xv_ = xv[j];
            float4 w0 = s_w0[c];
            float4 w1 = s_w1[c];
            a0 += xv_ * w0.x; a1 += xv_ * w0.y; a2 += xv_ * w0.z; a3 += xv_ * w0.w;
            aq += xv_ * s_b0[c];
            c0 += xv_ * w1.x; c1 += xv_ * w1.y; c2 += xv_ * w1.z; c3 += xv_ * w1.w;
            cq += xv_ * s_b1[c];
        }
    }
    H4 ps; ps.h[0] = __float2half_rn(a0); ps.h[1] = __float2half_rn(a1);
           ps.h[2] = __float2half_rn(a2); ps.h[3] = __float2half_rn(a3);
    H4 pd; pd.h[0] = __float2half_rn(c0); pd.h[1] = __float2half_rn(c1);
           pd.h[2] = __float2half_rn(c2); pd.h[3] = __float2half_rn(c3);
    H2 q;  q.h[0] = __float2half_rn(aq); q.h[1] = __float2half_rn(cq);
    ps_t[n] = ps.v;
    pd_t[n] = pd.v;
    q_t[n]  = q.v;
}

// Per-edge kernel. block=1024: VGPR small -> 2 blocks/CU = 32 waves/CU (100%
// occupancy). 4 L2-resident gathers/edge (8+8+4+4 B) replace 2x16 B from the
// old 3.2 MB table.
__global__ __launch_bounds__(ETHR) void edge_k(
    const int* __restrict__ ei,
    const float* __restrict__ sf,
    const int* __restrict__ layer_idx_p,
    const float* __restrict__ gamma_h,
    const uint2* __restrict__ ps_t,
    const uint2* __restrict__ pd_t,
    const unsigned int* __restrict__ q_t,
    float* __restrict__ out)
{
    __shared__ float s_g[HH];
    if (threadIdx.x < HH) {
        int li = layer_idx_p[0];
        s_g[threadIdx.x] = gamma_h[li * HH + threadIdx.x];
    }
    __syncthreads();

    int e = blockIdx.x * ETHR + threadIdx.x;
    if (e >= E_EDGES) return;

    int row = __builtin_nontemporal_load(ei + e);
    int col = __builtin_nontemporal_load(ei + E_EDGES + e);

    // Issue all four gathers before the streaming sf load so they overlap.
    H4 ps; ps.v = ps_t[row];       // p_src of row
    H4 pd; pd.v = pd_t[col];       // p_dst of col
    H2 qr; qr.v = q_t[row];        // (q_src, q_dst) of row -> use h[0]
    H2 qc; qc.v = q_t[col];        // -> use h[1]

    v4f f = __builtin_nontemporal_load((const v4f*)sf + e);

    float s = f.x * (__half2float(ps.h[0]) + __half2float(pd.h[0]))
            + f.y * (__half2float(ps.h[1]) + __half2float(pd.h[1]))
            + f.z * (__half2float(ps.h[2]) + __half2float(pd.h[2]))
            + f.w * (__half2float(ps.h[3]) + __half2float(pd.h[3]))
            + __half2float(qr.h[0]) + __half2float(qc.h[1]);
    float base = (s > 0.0f) ? s : 0.01f * s;

    v4f o0 = { s_g[0] * base, s_g[1] * base, s_g[2] * base, s_g[3] * base };
    v4f o1 = { s_g[4] * base, s_g[5] * base, s_g[6] * base, s_g[7] * base };
    v4f* op = (v4f*)(out + (size_t)e * HH);
    __builtin_nontemporal_store(o0, op);
    __builtin_nontemporal_store(o1, op + 1);
}

extern "C" void kernel_launch(void* const* d_in, const int* in_sizes, int n_in,
                              void* d_out, int out_size, void* d_ws, size_t ws_size,
                              hipStream_t stream) {
    const float* x       = (const float*)d_in[0];
    const int*   ei      = (const int*)d_in[1];
    const float* sf      = (const float*)d_in[2];
    const int*   li      = (const int*)d_in[3];
    const float* psi_w   = (const float*)d_in[4];
    const float* psi_b   = (const float*)d_in[5];
    const float* delta_w = (const float*)d_in[6];
    const float* u       = (const float*)d_in[7];
    const float* gamma_h = (const float*)d_in[8];
    float* out = (float*)d_out;

    uint2* ps_t = (uint2*)d_ws;                            // 0.8 MB
    uint2* pd_t = ps_t + N_NODES;                          // 0.8 MB
    unsigned int* q_t = (unsigned int*)(pd_t + N_NODES);   // 0.4 MB

    node_pre<<<(N_NODES + 255) / 256, 256, 0, stream>>>(
        x, li, psi_w, psi_b, delta_w, u, ps_t, pd_t, q_t);

    edge_k<<<(E_EDGES + ETHR - 1) / ETHR, ETHR, 0, stream>>>(
        ei, sf, li, gamma_h, ps_t, pd_t, q_t, out);
}

// Round 3
// 159.306 us; speedup vs baseline: 1.0377x; 1.0377x over previous
//
#include <hip/hip_runtime.h>
#include <hip/hip_fp16.h>

#define N_NODES 100000
#define CCH 64
#define E_EDGES 1600000
#define HH 8
#define ETHR 512   // edge-kernel block size: 8 waves/block, 4 blocks/CU -> 32 waves/CU
#define EPT 2      // edges per thread: doubles in-flight gathers per wave (latency-bound regime)

typedef float v4f __attribute__((ext_vector_type(4)));
typedef int   v2i __attribute__((ext_vector_type(2)));   // native clang vector: OK for nontemporal builtins

// Unified interleaved table: node n -> 32 B = [srcRec 16 B | dstRec 16 B].
// Each record: p[4], q as fp16 (+3 pad). Total 3.2 MB -> L2-resident (round-1
// FETCH_SIZE=26.6MB < streaming-ideal 38.4MB proves gathers were hitting cache).
// 2 gathers + 2 lines per edge is the minimum (one per endpoint); the round-1
// split-table layout (4 gathers, 4 lines) regressed edge_k 40->54 us.
union RecU {
    uint4  v;
    __half h[8];
};

__global__ __launch_bounds__(256) void node_pre(
    const float* __restrict__ x,
    const int* __restrict__ layer_idx_p,
    const float* __restrict__ psi_w,
    const float* __restrict__ psi_b,
    const float* __restrict__ delta_w,
    const float* __restrict__ u,
    uint4* __restrict__ recs)          // recs[2n] = src, recs[2n+1] = dst
{
    __shared__ float4 s_w0[CCH];
    __shared__ float4 s_w1[CCH];
    __shared__ float  s_b0[CCH];
    __shared__ float  s_b1[CCH];

    int li = layer_idx_p[0];
    for (int i = threadIdx.x; i < 2 * CCH; i += blockDim.x) {
        float4 w = make_float4(psi_w[i * 4 + 0], psi_w[i * 4 + 1],
                               psi_w[i * 4 + 2], psi_w[i * 4 + 3]);
        float bb = psi_b[i] + delta_w[li * 2 * CCH + i] + u[li * 2 * CCH + i];
        if (i < CCH) { s_w0[i] = w; s_b0[i] = bb; }
        else         { s_w1[i - CCH] = w; s_b1[i - CCH] = bb; }
    }
    __syncthreads();

    int n = blockIdx.x * blockDim.x + threadIdx.x;
    if (n >= N_NODES) return;

    const float4* xr = (const float4*)(x + (size_t)n * CCH);
    float a0 = 0, a1 = 0, a2 = 0, a3 = 0, aq = 0;
    float c0 = 0, c1 = 0, c2 = 0, c3 = 0, cq = 0;
#pragma unroll
    for (int it = 0; it < CCH / 4; ++it) {
        float4 xv4 = xr[it];
        float xv[4] = { xv4.x, xv4.y, xv4.z, xv4.w };
#pragma unroll
        for (int j = 0; j < 4; ++j) {
            int c = it * 4 + j;
            float xv_ = xv[j];
            float4 w0 = s_w0[c];
            float4 w1 = s_w1[c];
            a0 += xv_ * w0.x; a1 += xv_ * w0.y; a2 += xv_ * w0.z; a3 += xv_ * w0.w;
            aq += xv_ * s_b0[c];
            c0 += xv_ * w1.x; c1 += xv_ * w1.y; c2 += xv_ * w1.z; c3 += xv_ * w1.w;
            cq += xv_ * s_b1[c];
        }
    }
    RecU rs;
    rs.h[0] = __float2half_rn(a0); rs.h[1] = __float2half_rn(a1);
    rs.h[2] = __float2half_rn(a2); rs.h[3] = __float2half_rn(a3);
    rs.h[4] = __float2half_rn(aq);
    rs.h[5] = __half(0.0f); rs.h[6] = __half(0.0f); rs.h[7] = __half(0.0f);
    RecU rd;
    rd.h[0] = __float2half_rn(c0); rd.h[1] = __float2half_rn(c1);
    rd.h[2] = __float2half_rn(c2); rd.h[3] = __float2half_rn(c3);
    rd.h[4] = __float2half_rn(cq);
    rd.h[5] = __half(0.0f); rd.h[6] = __half(0.0f); rd.h[7] = __half(0.0f);
    recs[2 * (size_t)n]     = rs.v;
    recs[2 * (size_t)n + 1] = rd.v;
}

// Per-edge kernel, 2 edges/thread. Latency-bound regime (18.7% HBM, 2.9% VALU):
// cost = gather transactions + exposed ei->gather chain latency. 2 gathers/edge
// is minimal; EPT=2 gives each wave 4 outstanding gathers + halves ei instrs.
__global__ __launch_bounds__(ETHR) void edge_k(
    const int* __restrict__ ei,
    const float* __restrict__ sf,
    const int* __restrict__ layer_idx_p,
    const float* __restrict__ gamma_h,
    const uint4* __restrict__ recs,
    float* __restrict__ out)
{
    __shared__ float s_g[HH];
    if (threadIdx.x < HH) {
        int li = layer_idx_p[0];
        s_g[threadIdx.x] = gamma_h[li * HH + threadIdx.x];
    }
    __syncthreads();

    int e0 = blockIdx.x * (ETHR * EPT) + 2 * threadIdx.x;  // handles e0, e0+1
    int pidx = e0 >> 1;
    bool live = (e0 < E_EDGES);        // E even, e0 even -> e0+1 also < E iff live
    if (!live) pidx = 0;               // tail: safe redundant loads, stores guarded

    // Coalesced pair loads: lane i reads ints [2i,2i+1] -> 512 B/wave contiguous.
    v2i r2 = __builtin_nontemporal_load((const v2i*)ei + pidx);
    v2i c2 = __builtin_nontemporal_load((const v2i*)(ei + E_EDGES) + pidx);

    // Independent streaming loads issue before the ei wait.
    const v4f* sfp = (const v4f*)sf + 2 * (size_t)pidx;
    v4f f0 = __builtin_nontemporal_load(sfp);
    v4f f1 = __builtin_nontemporal_load(sfp + 1);

    // 4 in-flight gathers (2 per edge, the minimum: one line per endpoint).
    RecU rs0; rs0.v = recs[2 * (size_t)r2.x];
    RecU rd0; rd0.v = recs[2 * (size_t)c2.x + 1];
    RecU rs1; rs1.v = recs[2 * (size_t)r2.y];
    RecU rd1; rd1.v = recs[2 * (size_t)c2.y + 1];

    float s0 = f0.x * (__half2float(rs0.h[0]) + __half2float(rd0.h[0]))
             + f0.y * (__half2float(rs0.h[1]) + __half2float(rd0.h[1]))
             + f0.z * (__half2float(rs0.h[2]) + __half2float(rd0.h[2]))
             + f0.w * (__half2float(rs0.h[3]) + __half2float(rd0.h[3]))
             + __half2float(rs0.h[4]) + __half2float(rd0.h[4]);
    float s1 = f1.x * (__half2float(rs1.h[0]) + __half2float(rd1.h[0]))
             + f1.y * (__half2float(rs1.h[1]) + __half2float(rd1.h[1]))
             + f1.z * (__half2float(rs1.h[2]) + __half2float(rd1.h[2]))
             + f1.w * (__half2float(rs1.h[3]) + __half2float(rd1.h[3]))
             + __half2float(rs1.h[4]) + __half2float(rd1.h[4]);
    float b0 = (s0 > 0.0f) ? s0 : 0.01f * s0;
    float b1 = (s1 > 0.0f) ? s1 : 0.01f * s1;

    if (live) {
        v4f o00 = { s_g[0] * b0, s_g[1] * b0, s_g[2] * b0, s_g[3] * b0 };
        v4f o01 = { s_g[4] * b0, s_g[5] * b0, s_g[6] * b0, s_g[7] * b0 };
        v4f o10 = { s_g[0] * b1, s_g[1] * b1, s_g[2] * b1, s_g[3] * b1 };
        v4f o11 = { s_g[4] * b1, s_g[5] * b1, s_g[6] * b1, s_g[7] * b1 };
        v4f* op = (v4f*)(out + (size_t)e0 * HH);   // 64 B contiguous per thread
        __builtin_nontemporal_store(o00, op);
        __builtin_nontemporal_store(o01, op + 1);
        __builtin_nontemporal_store(o10, op + 2);
        __builtin_nontemporal_store(o11, op + 3);
    }
}

extern "C" void kernel_launch(void* const* d_in, const int* in_sizes, int n_in,
                              void* d_out, int out_size, void* d_ws, size_t ws_size,
                              hipStream_t stream) {
    const float* x       = (const float*)d_in[0];
    const int*   ei      = (const int*)d_in[1];
    const float* sf      = (const float*)d_in[2];
    const int*   li      = (const int*)d_in[3];
    const float* psi_w   = (const float*)d_in[4];
    const float* psi_b   = (const float*)d_in[5];
    const float* delta_w = (const float*)d_in[6];
    const float* u       = (const float*)d_in[7];
    const float* gamma_h = (const float*)d_in[8];
    float* out = (float*)d_out;

    uint4* recs = (uint4*)d_ws;   // 2 * N * 16 B = 3.2 MB interleaved table

    node_pre<<<(N_NODES + 255) / 256, 256, 0, stream>>>(
        x, li, psi_w, psi_b, delta_w, u, recs);

    const int edges_per_block = ETHR * EPT;
    edge_k<<<(E_EDGES + edges_per_block - 1) / edges_per_block, ETHR, 0, stream>>>(
        ei, sf, li, gamma_h, recs, out);
}

// Round 4
// 143.320 us; speedup vs baseline: 1.1535x; 1.1115x over previous
//
#include <hip/hip_runtime.h>
#include <hip/hip_fp16.h>

#define N_NODES 100000
#define CCH 64
#define E_EDGES 1600000
#define HH 8
#define ETHR 1024   // 16 waves/block, 2 blocks/CU -> 32 waves/CU

typedef float v4f __attribute__((ext_vector_type(4)));

// Unified interleaved table: node n -> 32 B = [srcRec 16 B | dstRec 16 B].
// Each record: p[4], q as fp16 (+3 pad). Total 3.2 MB -> L2-resident.
// 2 gathers + 2 lines per edge is the minimum (one line per endpoint).
// Ledger: round0 (EPT=1, dense loads, stride-32B stores)       edge_k ~32.3 us
//         round1 (split tables: 4 gathers/edge)                edge_k  54   us
//         round3 (EPT=2: stride-64B stores, half-dense sf)     edge_k  46   us, WRITE 72MB (1.4x ampl.)
// => transaction/issue patterns dominate; this round: round0 + LDS-staged fully-dense stores.
union RecU {
    uint4  v;
    __half h[8];
};

__global__ __launch_bounds__(256) void node_pre(
    const float* __restrict__ x,
    const int* __restrict__ layer_idx_p,
    const float* __restrict__ psi_w,
    const float* __restrict__ psi_b,
    const float* __restrict__ delta_w,
    const float* __restrict__ u,
    uint4* __restrict__ recs)          // recs[2n] = src, recs[2n+1] = dst
{
    __shared__ float4 s_w0[CCH];
    __shared__ float4 s_w1[CCH];
    __shared__ float  s_b0[CCH];
    __shared__ float  s_b1[CCH];

    int li = layer_idx_p[0];
    for (int i = threadIdx.x; i < 2 * CCH; i += blockDim.x) {
        float4 w = make_float4(psi_w[i * 4 + 0], psi_w[i * 4 + 1],
                               psi_w[i * 4 + 2], psi_w[i * 4 + 3]);
        float bb = psi_b[i] + delta_w[li * 2 * CCH + i] + u[li * 2 * CCH + i];
        if (i < CCH) { s_w0[i] = w; s_b0[i] = bb; }
        else         { s_w1[i - CCH] = w; s_b1[i - CCH] = bb; }
    }
    __syncthreads();

    int n = blockIdx.x * blockDim.x + threadIdx.x;
    if (n >= N_NODES) return;

    const float4* xr = (const float4*)(x + (size_t)n * CCH);
    float a0 = 0, a1 = 0, a2 = 0, a3 = 0, aq = 0;
    float c0 = 0, c1 = 0, c2 = 0, c3 = 0, cq = 0;
#pragma unroll
    for (int it = 0; it < CCH / 4; ++it) {
        float4 xv4 = xr[it];
        float xv[4] = { xv4.x, xv4.y, xv4.z, xv4.w };
#pragma unroll
        for (int j = 0; j < 4; ++j) {
            int c = it * 4 + j;
            float xv_ = xv[j];
            float4 w0 = s_w0[c];
            float4 w1 = s_w1[c];
            a0 += xv_ * w0.x; a1 += xv_ * w0.y; a2 += xv_ * w0.z; a3 += xv_ * w0.w;
            aq += xv_ * s_b0[c];
            c0 += xv_ * w1.x; c1 += xv_ * w1.y; c2 += xv_ * w1.z; c3 += xv_ * w1.w;
            cq += xv_ * s_b1[c];
        }
    }
    RecU rs;
    rs.h[0] = __float2half_rn(a0); rs.h[1] = __float2half_rn(a1);
    rs.h[2] = __float2half_rn(a2); rs.h[3] = __float2half_rn(a3);
    rs.h[4] = __float2half_rn(aq);
    rs.h[5] = __half(0.0f); rs.h[6] = __half(0.0f); rs.h[7] = __half(0.0f);
    RecU rd;
    rd.h[0] = __float2half_rn(c0); rd.h[1] = __float2half_rn(c1);
    rd.h[2] = __float2half_rn(c2); rd.h[3] = __float2half_rn(c3);
    rd.h[4] = __float2half_rn(cq);
    rd.h[5] = __half(0.0f); rd.h[6] = __half(0.0f); rd.h[7] = __half(0.0f);
    recs[2 * (size_t)n]     = rs.v;
    recs[2 * (size_t)n + 1] = rd.v;
}

// Per-edge kernel, round-0 structure (1 edge/thread, all loads fully dense,
// 2 gathers/edge) + LDS base-stage so the store phase is 100% dense:
// each store instruction = 64 lanes x 16 B contiguous = 1 KB, full lines only.
__global__ __launch_bounds__(ETHR) void edge_k(
    const int* __restrict__ ei,
    const float* __restrict__ sf,
    const int* __restrict__ layer_idx_p,
    const float* __restrict__ gamma_h,
    const uint4* __restrict__ recs,
    float* __restrict__ out)
{
    __shared__ float s_g[HH];
    __shared__ float s_b[ETHR];

    if (threadIdx.x < HH) {
        int li = layer_idx_p[0];
        s_g[threadIdx.x] = gamma_h[li * HH + threadIdx.x];
    }

    int e  = blockIdx.x * ETHR + threadIdx.x;
    int ee = (e < E_EDGES) ? e : (E_EDGES - 1);   // clamp: safe redundant work in tail

    int row = __builtin_nontemporal_load(ei + ee);              // 4 B/lane dense
    int col = __builtin_nontemporal_load(ei + E_EDGES + ee);    // 4 B/lane dense
    v4f f   = __builtin_nontemporal_load((const v4f*)sf + ee);  // 16 B/lane dense

    RecU rs; rs.v = recs[2 * (size_t)row];       // src record of row (16 B gather)
    RecU rd; rd.v = recs[2 * (size_t)col + 1];   // dst record of col (16 B gather)

    float s = f.x * (__half2float(rs.h[0]) + __half2float(rd.h[0]))
            + f.y * (__half2float(rs.h[1]) + __half2float(rd.h[1]))
            + f.z * (__half2float(rs.h[2]) + __half2float(rd.h[2]))
            + f.w * (__half2float(rs.h[3]) + __half2float(rd.h[3]))
            + __half2float(rs.h[4]) + __half2float(rd.h[4]);
    float base = (s > 0.0f) ? s : 0.01f * s;

    s_b[threadIdx.x] = base;
    __syncthreads();   // single barrier: covers s_g and s_b

    // Store phase: block owns 2*ETHR v4f slabs. v4f local index l -> edge l>>1,
    // gamma-half l&1. Thread t writes l=t and l=t+ETHR (same half t&1).
    int t = threadIdx.x;
    float b0v = s_b[t >> 1];                  // 2-way same-address broadcast: conflict-free
    float b1v = s_b[(t >> 1) + (ETHR / 2)];
    const int go = (t & 1) * 4;
    float g0 = s_g[go + 0], g1 = s_g[go + 1], g2 = s_g[go + 2], g3 = s_g[go + 3];
    v4f o0 = { g0 * b0v, g1 * b0v, g2 * b0v, g3 * b0v };
    v4f o1 = { g0 * b1v, g1 * b1v, g2 * b1v, g3 * b1v };

    size_t vbase = (size_t)blockIdx.x * (2 * ETHR);
    v4f* op = (v4f*)out;
    int e0 = blockIdx.x * ETHR + (t >> 1);    // edge of first write
    if (e0 < E_EDGES)
        __builtin_nontemporal_store(o0, op + vbase + t);
    if (e0 + ETHR / 2 < E_EDGES)
        __builtin_nontemporal_store(o1, op + vbase + ETHR + t);
}

extern "C" void kernel_launch(void* const* d_in, const int* in_sizes, int n_in,
                              void* d_out, int out_size, void* d_ws, size_t ws_size,
                              hipStream_t stream) {
    const float* x       = (const float*)d_in[0];
    const int*   ei      = (const int*)d_in[1];
    const float* sf      = (const float*)d_in[2];
    const int*   li      = (const int*)d_in[3];
    const float* psi_w   = (const float*)d_in[4];
    const float* psi_b   = (const float*)d_in[5];
    const float* delta_w = (const float*)d_in[6];
    const float* u       = (const float*)d_in[7];
    const float* gamma_h = (const float*)d_in[8];
    float* out = (float*)d_out;

    uint4* recs = (uint4*)d_ws;   // 2 * N * 16 B = 3.2 MB interleaved table

    node_pre<<<(N_NODES + 255) / 256, 256, 0, stream>>>(
        x, li, psi_w, psi_b, delta_w, u, recs);

    edge_k<<<(E_EDGES + ETHR - 1) / ETHR, ETHR, 0, stream>>>(
        ei, sf, li, gamma_h, recs, out);
}